// Round 5
// baseline (24.173 us; speedup 1.0000x reference)
//
#include <hip/hip_runtime.h>

// ---------------------------------------------------------------------------
// plan[b,t,a] = sum_s H_ty[t][s]*tgt[b,s,a] + sum_j G_ty[t][j]*x0[j][b,a]
// ty(a): axes 0,1 -> type 0, axis 2 (yaw) -> type 1. H (80x80) and G (80x3)
// per type computed AT COMPILE TIME in double precision. Stored t-PADDED:
// col(t) = (t/10)*12 + t%10, so each 10-wide t-tile starts 48B-aligned ->
// three float4 loads per row (vmcnt-prefetchable vector loads, no SMEM).
// ---------------------------------------------------------------------------
struct BasisP {
    float HT[80][96];   // HT[s][col(t)]
    float GT[3][96];    // GT[j][col(t)]
};

template <int TY>
constexpr BasisP build_basis() {
    BasisP B{};
    const double dt = 0.1, dt2 = 0.01, dt3 = 0.001;
    const double cxp = TY ? 10.0 : 1.0;    // YAW_W vs 1
    const double cxv = TY ? 1.0 : 0.0;     // YAW_VEL_W vs 0
    const double w   = TY ? 10.0 : 1.0;    // target pre-scale (yaw *= YAW_W)

    double qx0[81] = {}, qx1[81] = {}, qx2[81] = {}, mm[81] = {};
    double kg0[81] = {}, kg1[81] = {}, kg2[81] = {};
    {
        double v00=0, v01=0, v02=0, v11=0, v12=0, v22=0;
        for (int t = 80; t >= 0; --t) {
            const double on = (t >= 1) ? 1.0 : 0.0;
            double Vb0 = v00*dt3 + v01*dt2 + v02*dt;
            double Vb1 = v01*dt3 + v11*dt2 + v12*dt;
            double Vb2 = v02*dt3 + v12*dt2 + v22*dt;
            double Quu = on*0.1 + dt3*Vb0 + dt2*Vb1 + dt*Vb2;
            double Qxu0 = Vb0;
            double Qxu1 = dt*Vb0 + Vb1;
            double Qxu2 = dt2*Vb0 + dt*Vb1 + Vb2;
            double M01 = dt*v00 + v01;
            double M02 = dt2*v00 + dt*v01 + v02;
            double M11 = dt*v01 + v11;
            double M12 = dt2*v01 + dt*v11 + v12;
            double M22 = dt2*v02 + dt*v12 + v22;
            double Q00 = on*cxp + v00;
            double Q11 = on*cxv + dt*M01 + M11;
            double Q12 = dt*M02 + M12;
            double Q22 = on*1.0 + dt2*M02 + dt*M12 + M22;
            double m = -1.0 / Quu;
            qx0[t] = Qxu0; qx1[t] = Qxu1; qx2[t] = Qxu2; mm[t] = m;
            kg0[t] = Qxu0*m; kg1[t] = Qxu1*m; kg2[t] = Qxu2*m;
            v00 = Q00 + m*Qxu0*Qxu0;
            v01 = M01 + m*Qxu0*Qxu1;
            v02 = M02 + m*Qxu0*Qxu2;
            v11 = Q11 + m*Qxu1*Qxu1;
            v12 = Q12 + m*Qxu1*Qxu2;
            v22 = Q22 + m*Qxu2*Qxu2;
        }
    }
    for (int sc = 0; sc < 80; ++sc) {
        double karr[80] = {};
        double v0 = 0, v1 = 0, v2 = 0;
        for (int t = sc + 1; t >= 1; --t) {
            double c  = (t - 1 == sc) ? -w : 0.0;
            double a1 = dt*v0 + v1;
            double a2 = dt*a1 + v2;
            double k  = dt*a2*mm[t];
            if (t <= 79) karr[t] = k;
            v0 = (c + v0) + qx0[t]*k;
            v1 = a1 + qx1[t]*k;
            v2 = a2 + qx2[t]*k;
        }
        {
            double a1 = dt*v0 + v1;
            double a2 = dt*a1 + v2;
            karr[0] = dt*a2*mm[0];
        }
        double p = 0, ve = 0, ac = 0;
        for (int t = 0; t < 80; ++t) {
            double u  = kg0[t]*p + kg1[t]*ve + kg2[t]*ac + karr[t];
            double pn = p + dt*ve + dt2*ac + dt3*u;
            double vn = ve + dt*ac + dt2*u;
            ac = ac + dt*u;
            p = pn; ve = vn;
            B.HT[sc][(t/10)*12 + t%10] = (float)p;
        }
    }
    for (int j = 0; j < 3; ++j) {
        double p = (j == 0), ve = (j == 1), ac = (j == 2);
        for (int t = 0; t < 80; ++t) {
            double u  = kg0[t]*p + kg1[t]*ve + kg2[t]*ac;
            double pn = p + dt*ve + dt2*ac + dt3*u;
            double vn = ve + dt*ac + dt2*u;
            ac = ac + dt*u;
            p = pn; ve = vn;
            B.GT[j][(t/10)*12 + t%10] = (float)p;
        }
    }
    return B;
}

__device__ constexpr BasisP g_b0 = build_basis<0>();   // axes x, y
__device__ constexpr BasisP g_b1 = build_basis<1>();   // yaw

// ---------------------------------------------------------------------------
// Apply kernel, K-split for occupancy. Grid 512 = 2 t-halves x 256 groups of
// 32 batches; bid = th*256 + g keeps a group's two halves on one XCD (bid%8
// equal) for L2 reuse of the duplicated target fetch. Block 256 thr = 4 waves:
// sg = tid>>7 (s-half 0..39 / 40..79), tau = (tid>>5)&3 (10-t subtile,
// half-wave-uniform -> H loads broadcast), bb = tid&31 (batch).
// Targets in LDS column-major sm[f*33+bb] (odd stride: compute reads hit all
// 32 banks). Partial sums exchanged through two LDS planes, then float4
// coalesced writeback. 2 waves/SIMD hide load latency.
// ---------------------------------------------------------------------------
#define NTH 256

__global__ __launch_bounds__(NTH) void lqr_apply_kernel(
        const float* __restrict__ ego,   // (8192, 9)
        const float* __restrict__ ap,    // (8192, 6, 80, 3)
        float* __restrict__ out) {       // (8192, 80, 3)
    __shared__ float sm[8208];           // 240*33 targets | 288 ego; reused
    const int tid = threadIdx.x;
    const int bid = blockIdx.x;
    const int th  = bid >> 8;            // t-half
    const int g   = bid & 255;           // batch group
    const int b0  = g * 32;

    // ---- stage targets: 32 batches x 60 float4, coalesced ----
    for (int i = tid; i < 1920; i += NTH) {
        int bb = i / 60, c = i - bb * 60;
        float4 v = *(const float4*)(ap + (size_t)(b0 + bb) * 1440 + 1200 + 4*c);
        sm[(4*c+0)*33 + bb] = v.x;
        sm[(4*c+1)*33 + bb] = v.y;
        sm[(4*c+2)*33 + bb] = v.z;
        sm[(4*c+3)*33 + bb] = v.w;
    }
    // ---- stage ego slice (contiguous 1152B) ----
    for (int i = tid; i < 288; i += NTH)
        sm[7920 + i] = ego[(size_t)b0 * 9 + i];
    __syncthreads();

    const int bb  = tid & 31;
    const int tau = (tid >> 5) & 3;
    const int sg  = tid >> 7;            // s-half (wave-uniform)
    const int col = (th * 4 + tau) * 12; // padded col base, 48B-aligned

    float a0[10], a1[10], a2[10];
    if (sg == 0) {
        const float* e9 = &sm[7920 + bb * 9];
        float xp0=e9[0], xp1=e9[1], xp2=e9[2];
        float xv0=e9[3], xv1=e9[4], xv2=e9[5];
        float xa0=e9[6], xa1=e9[7], xa2=e9[8];
        #pragma unroll
        for (int i = 0; i < 10; ++i) {
            float g00 = g_b0.GT[0][col+i], g01 = g_b0.GT[1][col+i], g02 = g_b0.GT[2][col+i];
            float g10 = g_b1.GT[0][col+i], g11 = g_b1.GT[1][col+i], g12 = g_b1.GT[2][col+i];
            a0[i] = fmaf(g00, xp0, fmaf(g01, xv0, g02 * xa0));
            a1[i] = fmaf(g00, xp1, fmaf(g01, xv1, g02 * xa1));
            a2[i] = fmaf(g10, xp2, fmaf(g11, xv2, g12 * xa2));
        }
    } else {
        #pragma unroll
        for (int i = 0; i < 10; ++i) { a0[i] = 0.f; a1[i] = 0.f; a2[i] = 0.f; }
    }

    const float* H0 = &g_b0.HT[0][col];  // row stride 96 floats
    const float* H1 = &g_b1.HT[0][col];
    const int sbase = sg * 40;
    #pragma unroll 2
    for (int si = 0; si < 40; ++si) {
        const int s = sbase + si;
        const float xv0 = sm[(3*s+0)*33 + bb];
        const float xv1 = sm[(3*s+1)*33 + bb];
        const float xv2 = sm[(3*s+2)*33 + bb];
        const float* h0 = H0 + s * 96;
        const float* h1 = H1 + s * 96;
        float ha[12], hb[12];
        *(float4*)&ha[0] = *(const float4*)(h0 + 0);
        *(float4*)&ha[4] = *(const float4*)(h0 + 4);
        *(float4*)&ha[8] = *(const float4*)(h0 + 8);
        *(float4*)&hb[0] = *(const float4*)(h1 + 0);
        *(float4*)&hb[4] = *(const float4*)(h1 + 4);
        *(float4*)&hb[8] = *(const float4*)(h1 + 8);
        #pragma unroll
        for (int i = 0; i < 10; ++i) {
            a0[i] = fmaf(ha[i], xv0, a0[i]);
            a1[i] = fmaf(ha[i], xv1, a1[i]);
            a2[i] = fmaf(hb[i], xv2, a2[i]);
        }
    }

    // ---- exchange partials via two LDS planes, then coalesced writeback ----
    __syncthreads();                     // targets/ego dead; reuse sm
    {
        float* plane = sm + sg * 3968;   // each plane: 120*33+31 < 3968
        const int fb = tau * 30;
        #pragma unroll
        for (int i = 0; i < 10; ++i) {
            plane[(fb + 3*i + 0)*33 + bb] = a0[i];
            plane[(fb + 3*i + 1)*33 + bb] = a1[i];
            plane[(fb + 3*i + 2)*33 + bb] = a2[i];
        }
    }
    __syncthreads();
    for (int i = tid; i < 960; i += NTH) {
        int bb2 = i / 30, c = i - bb2 * 30;
        float v[4];
        #pragma unroll
        for (int e = 0; e < 4; ++e) {
            int f = 4*c + e;
            v[e] = sm[f*33 + bb2] + sm[3968 + f*33 + bb2];
        }
        *(float4*)(out + (size_t)(b0 + bb2) * 240 + th * 120 + 4*c) =
            make_float4(v[0], v[1], v[2], v[3]);
    }
}

extern "C" void kernel_launch(void* const* d_in, const int* in_sizes, int n_in,
                              void* d_out, int out_size, void* d_ws, size_t ws_size,
                              hipStream_t stream) {
    const float* ego = (const float*)d_in[0];   // (8192, 9)
    const float* ap  = (const float*)d_in[1];   // (8192, 6, 80, 3)
    float*       out = (float*)d_out;           // (8192, 80, 3)
    lqr_apply_kernel<<<512, NTH, 0, stream>>>(ego, ap, out);
}

// Round 6
// 20.012 us; speedup vs baseline: 1.2079x; 1.2079x over previous
//
#include <hip/hip_runtime.h>

// ---------------------------------------------------------------------------
// 9-state/3-control LQR decouples per axis into a 3-state (p,v,a | jerk)
// chain; axes 0,1 = type 0, axis 2 (yaw) = type 1. The Riccati table is
// input-independent -> computed at COMPILE TIME in double precision and,
// via full loop unrolling + template-constant type, folded into the
// instruction stream as literal constants (zero memory traffic, zero
// waitcnt in the recursion's dependent chain).
// ---------------------------------------------------------------------------
struct Tbl {
    float qx0[81], qx1[81], qx2[81], dm[81];   // Qxu, dm = DT * (-1/Quu)
    float k0[81],  k1[81],  k2[81];            // feedback gains K_t
};

constexpr Tbl make_tbl(int TY) {
    Tbl T{};
    const double dt = 0.1, dt2 = 0.01, dt3 = 0.001;
    const double cxp = TY ? 10.0 : 1.0;        // YAW_W vs 1
    const double cxv = TY ? 1.0  : 0.0;        // YAW_VEL_W vs 0
    double v00=0, v01=0, v02=0, v11=0, v12=0, v22=0;
    for (int t = 80; t >= 0; --t) {
        const double on = (t >= 1) ? 1.0 : 0.0;     // C[0] == 0
        double Vb0 = v00*dt3 + v01*dt2 + v02*dt;
        double Vb1 = v01*dt3 + v11*dt2 + v12*dt;
        double Vb2 = v02*dt3 + v12*dt2 + v22*dt;
        double Quu = on*0.1 + dt3*Vb0 + dt2*Vb1 + dt*Vb2;
        double Qxu0 = Vb0;
        double Qxu1 = dt*Vb0 + Vb1;
        double Qxu2 = dt2*Vb0 + dt*Vb1 + Vb2;
        double M01 = dt*v00 + v01;
        double M02 = dt2*v00 + dt*v01 + v02;
        double M11 = dt*v01 + v11;
        double M12 = dt2*v01 + dt*v11 + v12;
        double M22 = dt2*v02 + dt*v12 + v22;
        double Q00 = on*cxp + v00;
        double Q11 = on*cxv + dt*M01 + M11;
        double Q12 = dt*M02 + M12;
        double Q22 = on*1.0 + dt2*M02 + dt*M12 + M22;
        double m = -1.0 / Quu;
        T.qx0[t] = (float)Qxu0; T.qx1[t] = (float)Qxu1; T.qx2[t] = (float)Qxu2;
        T.dm[t]  = (float)(dt * m);
        T.k0[t]  = (float)(Qxu0*m); T.k1[t] = (float)(Qxu1*m); T.k2[t] = (float)(Qxu2*m);
        v00 = Q00 + m*Qxu0*Qxu0;               // Vn = Qxx + m*Qxu*Qxu^T
        v01 = M01 + m*Qxu0*Qxu1;               // (Qux + Quu*K == 0)
        v02 = M02 + m*Qxu0*Qxu2;
        v11 = Q11 + m*Qxu1*Qxu1;
        v12 = Q12 + m*Qxu1*Qxu2;
        v22 = Q22 + m*Qxu2*Qxu2;
    }
    return T;
}

// Per-(batch,axis) recursion. TY is a compile-time constant; loops fully
// unrolled -> all table reads fold to literals, all LDS offsets constant.
template <int TY>
__device__ __forceinline__ void do_axis(float* __restrict__ row, const int axis,
                                        float p, float ve, float ac) {
    constexpr Tbl T = make_tbl(TY);
    constexpr float wp = TY ? 10.f : 1.f;

    // ---- backward: v-recursion; k_t overwrites the target slot it consumed
    float v0 = 0.f, v1 = 0.f, v2 = 0.f;
#pragma unroll
    for (int t = 80; t >= 1; --t) {
        const int s = (t - 1) * 3;
        float tg = row[s + axis];              // target (s = t-1)
        float a1 = fmaf(0.1f, v0, v1);
        float a2 = fmaf(0.1f, a1, v2);
        float k  = T.dm[t] * a2;               // k_t = -(b^T v)/Quu
        v0 = fmaf(T.qx0[t], k, v0) - wp * tg;
        v1 = fmaf(T.qx1[t], k, a1);
        v2 = fmaf(T.qx2[t], k, a2);
        row[s + axis] = k;                     // k_t -> slot t-1
    }
    {   // t = 0: C==0, only k_0 needed; park at slot 79 (k_80 never used)
        float a1 = fmaf(0.1f, v0, v1);
        float a2 = fmaf(0.1f, a1, v2);
        row[79 * 3 + axis] = T.dm[0] * a2;
    }

    // ---- forward rollout: read k_t, overwrite slot with p_t ----
#pragma unroll
    for (int t = 0; t < 80; ++t) {
        const int slot = ((t == 0) ? 79 : (t - 1)) * 3 + axis;
        float kk = row[slot];
        float u  = fmaf(T.k0[t], p, fmaf(T.k1[t], ve, fmaf(T.k2[t], ac, kk)));
        float pn = fmaf(0.001f, u, fmaf(0.01f, ac, fmaf(0.1f, ve, p)));
        float vn = fmaf(0.01f,  u, fmaf(0.1f,  ac, ve));
        ac = fmaf(0.1f, u, ac);
        p = pn; ve = vn;
        row[slot] = p;                         // p_t parked where k_t lived
    }
}

// ---------------------------------------------------------------------------
// Block = 96 threads, BPB = 32 batches, grid = 256 (1 block/CU).
// wave0 (tid 0..63)  = axes 0,1 for batches 0..31  -> type 0 path (uniform)
// wave1 (tid 64..95) = axis 2   for batches 0..31  -> type 1 path (uniform)
// LDS rows stride 240 floats (16B aligned; 240%32=16 -> 2-way = free).
// ---------------------------------------------------------------------------
#define BPB 32
#define RS  240
#define NTH 96

__global__ __launch_bounds__(NTH) void lqr_fused_kernel(
        const float* __restrict__ ego,   // (8192, 9)
        const float* __restrict__ ap,    // (8192, 6, 80, 3)
        float* __restrict__ out) {       // (8192, 80, 3)
    __shared__ float sm[BPB * RS + BPB * 9];   // 7680 + 288 floats = 31872 B
    const int tid = threadIdx.x;
    const int b0  = blockIdx.x * BPB;

    // ---- stage targets: 32 batches x 60 float4, coalesced ----
    for (int i = tid; i < BPB * 60; i += NTH) {
        int bb = i / 60, c = i - bb * 60;
        float4 v = *(const float4*)(ap + (size_t)(b0 + bb) * 1440 + 1200 + 4*c);
        *(float4*)&sm[bb * RS + 4*c] = v;
    }
    // ---- stage ego slice: contiguous 1152 B ----
    for (int i = tid; i < BPB * 9; i += NTH)
        sm[BPB * RS + i] = ego[(size_t)b0 * 9 + i];
    __syncthreads();

    const int axis = tid >> 5;           // 0,0 | 1,1 | 2  per half-wave
    const int bb   = tid & 31;
    float* row = sm + bb * RS;
    const float* e = sm + BPB * RS + bb * 9;
    const float xp = e[axis], xv = e[3 + axis], xa = e[6 + axis];

    if (tid < 64) do_axis<0>(row, axis, xp, xv, xa);   // wave0: axes 0,1
    else          do_axis<1>(row, 2,    xp, xv, xa);   // wave1: yaw
    __syncthreads();

    // ---- coalesced writeback: out[b][t][a] <- slot ((t?t-1:79)*3+a) ----
    for (int i = tid; i < BPB * 60; i += NTH) {
        int bb2 = i / 60, c = i - bb2 * 60;
        float v[4];
        #pragma unroll
        for (int e2 = 0; e2 < 4; ++e2) {
            int f = 4*c + e2;            // f = t*3 + a
            int t = f / 3, a = f - t * 3;
            int slot = ((t == 0) ? 79 : (t - 1)) * 3 + a;
            v[e2] = sm[bb2 * RS + slot];
        }
        *(float4*)(out + (size_t)(b0 + bb2) * 240 + 4*c) =
            make_float4(v[0], v[1], v[2], v[3]);
    }
}

extern "C" void kernel_launch(void* const* d_in, const int* in_sizes, int n_in,
                              void* d_out, int out_size, void* d_ws, size_t ws_size,
                              hipStream_t stream) {
    const float* ego = (const float*)d_in[0];   // (8192, 9)
    const float* ap  = (const float*)d_in[1];   // (8192, 6, 80, 3)
    float*       out = (float*)d_out;           // (8192, 80, 3)
    lqr_fused_kernel<<<8192 / BPB, NTH, 0, stream>>>(ego, ap, out);
}

// Round 7
// 14.551 us; speedup vs baseline: 1.6613x; 1.3753x over previous
//
#include <hip/hip_runtime.h>

// ---------------------------------------------------------------------------
// 9-state/3-control LQR decouples per axis into a 3-state (p,v,a | jerk)
// chain; axes 0,1 = type 0, axis 2 (yaw) = type 1. Riccati table computed at
// COMPILE TIME (double precision) and folded to literals via full unroll.
// This round: the recursion's dependent chain is REGISTER-ONLY — LDS is used
// only for coalesced staging/writeback (addresses compile-time constant, off
// the chain). k_t lives in a fully-unrolled register array kk[80].
// ---------------------------------------------------------------------------
struct Tbl {
    float qx0[81], qx1[81], qx2[81], dm[81];   // Qxu, dm = DT * (-1/Quu)
    float k0[81],  k1[81],  k2[81];            // feedback gains K_t
};

constexpr Tbl make_tbl(int TY) {
    Tbl T{};
    const double dt = 0.1, dt2 = 0.01, dt3 = 0.001;
    const double cxp = TY ? 10.0 : 1.0;        // YAW_W vs 1
    const double cxv = TY ? 1.0  : 0.0;        // YAW_VEL_W vs 0
    double v00=0, v01=0, v02=0, v11=0, v12=0, v22=0;
    for (int t = 80; t >= 0; --t) {
        const double on = (t >= 1) ? 1.0 : 0.0;     // C[0] == 0
        double Vb0 = v00*dt3 + v01*dt2 + v02*dt;
        double Vb1 = v01*dt3 + v11*dt2 + v12*dt;
        double Vb2 = v02*dt3 + v12*dt2 + v22*dt;
        double Quu = on*0.1 + dt3*Vb0 + dt2*Vb1 + dt*Vb2;
        double Qxu0 = Vb0;
        double Qxu1 = dt*Vb0 + Vb1;
        double Qxu2 = dt2*Vb0 + dt*Vb1 + Vb2;
        double M01 = dt*v00 + v01;
        double M02 = dt2*v00 + dt*v01 + v02;
        double M11 = dt*v01 + v11;
        double M12 = dt2*v01 + dt*v11 + v12;
        double M22 = dt2*v02 + dt*v12 + v22;
        double Q00 = on*cxp + v00;
        double Q11 = on*cxv + dt*M01 + M11;
        double Q12 = dt*M02 + M12;
        double Q22 = on*1.0 + dt2*M02 + dt*M12 + M22;
        double m = -1.0 / Quu;
        T.qx0[t] = (float)Qxu0; T.qx1[t] = (float)Qxu1; T.qx2[t] = (float)Qxu2;
        T.dm[t]  = (float)(dt * m);
        T.k0[t]  = (float)(Qxu0*m); T.k1[t] = (float)(Qxu1*m); T.k2[t] = (float)(Qxu2*m);
        v00 = Q00 + m*Qxu0*Qxu0;               // Vn = Qxx + m*Qxu*Qxu^T
        v01 = M01 + m*Qxu0*Qxu1;               // (Qux + Quu*K == 0)
        v02 = M02 + m*Qxu0*Qxu2;
        v11 = Q11 + m*Qxu1*Qxu1;
        v12 = Q12 + m*Qxu1*Qxu2;
        v22 = Q22 + m*Qxu2*Qxu2;
    }
    return T;
}

// Register-resident recursion. `row` = &sm[bb*RS + axis]; all offsets
// compile-time constants after unroll; kk[] indices constant -> VGPRs.
template <int TY>
__device__ __forceinline__ void do_axis(float* __restrict__ row,
                                        float p, float ve, float ac) {
    constexpr Tbl T = make_tbl(TY);
    constexpr float wp = TY ? 10.f : 1.f;
    float kk[80];

    // ---- backward: v-recursion in registers; tg reads are off-chain ----
    float v0 = 0.f, v1 = 0.f, v2 = 0.f;
#pragma unroll
    for (int t = 80; t >= 1; --t) {
        float tg = row[(t - 1) * 3];           // independent address, batchable
        float a1 = fmaf(0.1f, v0, v1);
        float a2 = fmaf(0.1f, a1, v2);
        float k  = T.dm[t] * a2;               // k_t = -(b^T v)/Quu
        v0 = fmaf(T.qx0[t], k, v0) - wp * tg;
        v1 = fmaf(T.qx1[t], k, a1);
        v2 = fmaf(T.qx2[t], k, a2);
        if (t <= 79) kk[t] = k;                // k_80 never used by forward
    }
    {   // t = 0: C==0
        float a1 = fmaf(0.1f, v0, v1);
        float a2 = fmaf(0.1f, a1, v2);
        kk[0] = T.dm[0] * a2;
    }

    // ---- forward rollout: pure-register; p_t lands in OUTPUT layout ----
#pragma unroll
    for (int t = 0; t < 80; ++t) {
        float u  = fmaf(T.k0[t], p, fmaf(T.k1[t], ve, fmaf(T.k2[t], ac, kk[t])));
        float pn = fmaf(0.001f, u, fmaf(0.01f, ac, fmaf(0.1f, ve, p)));
        float vn = fmaf(0.01f,  u, fmaf(0.1f,  ac, ve));
        ac = fmaf(0.1f, u, ac);
        p = pn; ve = vn;
        row[t * 3] = p;                        // slot t*3+axis == out[t][axis]
    }
}

// ---------------------------------------------------------------------------
// Block = 96 threads (wave0: axes 0,1 x 32 batches; half-wave1: axis 2),
// BPB = 32, grid = 256 (1 block/CU).
// LDS row stride 244 floats: 16B-aligned; 244%32=20 -> recursion-phase scalar
// accesses spread over 8 bank groups (<=4-way, 1.58x) vs R6's 16-way.
// Staging and writeback are contiguous float4 (the forward pass writes
// position directly in out-layout, so writeback is a straight copy).
// ---------------------------------------------------------------------------
#define BPB 32
#define RS  244
#define NTH 96

__global__ __launch_bounds__(NTH) void lqr_fused_kernel(
        const float* __restrict__ ego,   // (8192, 9)
        const float* __restrict__ ap,    // (8192, 6, 80, 3)
        float* __restrict__ out) {       // (8192, 80, 3)
    __shared__ float sm[BPB * RS];       // 31232 B
    const int tid = threadIdx.x;
    const int b0  = blockIdx.x * BPB;

    // ---- stage targets: 32 batches x 60 float4, coalesced, contiguous ----
    for (int i = tid; i < BPB * 60; i += NTH) {
        int bb = i / 60, c = i - bb * 60;
        *(float4*)&sm[bb * RS + 4 * c] =
            *(const float4*)(ap + (size_t)(b0 + bb) * 1440 + 1200 + 4 * c);
    }
    __syncthreads();

    const int axis = tid >> 5;           // 0,0 | 1,1 | 2 per half-wave
    const int bb   = tid & 31;
    const int b    = b0 + bb;
    // ego loads: issued here, consumed only at forward start (long slack)
    const float xp = ego[b * 9 + axis];
    const float xv = ego[b * 9 + 3 + axis];
    const float xa = ego[b * 9 + 6 + axis];
    float* row = sm + bb * RS + axis;

    if (tid < 64) do_axis<0>(row, xp, xv, xa);   // wave0: axes 0,1 (type 0)
    else          do_axis<1>(row, xp, xv, xa);   // half-wave1: yaw (type 1)
    __syncthreads();

    // ---- writeback: straight contiguous copy (already in out layout) ----
    for (int i = tid; i < BPB * 60; i += NTH) {
        int bb2 = i / 60, c = i - bb2 * 60;
        *(float4*)(out + (size_t)(b0 + bb2) * 240 + 4 * c) =
            *(const float4*)&sm[bb2 * RS + 4 * c];
    }
}

extern "C" void kernel_launch(void* const* d_in, const int* in_sizes, int n_in,
                              void* d_out, int out_size, void* d_ws, size_t ws_size,
                              hipStream_t stream) {
    const float* ego = (const float*)d_in[0];   // (8192, 9)
    const float* ap  = (const float*)d_in[1];   // (8192, 6, 80, 3)
    float*       out = (float*)d_out;           // (8192, 80, 3)
    lqr_fused_kernel<<<8192 / BPB, NTH, 0, stream>>>(ego, ap, out);
}

// Round 8
// 11.487 us; speedup vs baseline: 2.1044x; 1.2667x over previous
//
#include <hip/hip_runtime.h>

// ---------------------------------------------------------------------------
// 9-state/3-control LQR decouples per axis into a 3-state (p,v,a | jerk)
// chain; axes 0,1 = type 0, axis 2 (yaw) = type 1. Riccati table computed at
// COMPILE TIME (double precision) and folded to literals via full unroll +
// template-constant type. Recursion dependent chain is REGISTER-ONLY (kk[80]
// constant-indexed -> VGPRs); LDS only for coalesced staging/writeback.
// This round: BPB 32->16, grid 256->512 => 2 blocks/CU so one block's
// staging/writeback (memory phases) overlaps the other's recursion (VALU
// latency chain). Math identical to R7 (validated, absmax 0.0078).
// ---------------------------------------------------------------------------
struct Tbl {
    float qx0[81], qx1[81], qx2[81], dm[81];   // Qxu, dm = DT * (-1/Quu)
    float k0[81],  k1[81],  k2[81];            // feedback gains K_t
};

constexpr Tbl make_tbl(int TY) {
    Tbl T{};
    const double dt = 0.1, dt2 = 0.01, dt3 = 0.001;
    const double cxp = TY ? 10.0 : 1.0;        // YAW_W vs 1
    const double cxv = TY ? 1.0  : 0.0;        // YAW_VEL_W vs 0
    double v00=0, v01=0, v02=0, v11=0, v12=0, v22=0;
    for (int t = 80; t >= 0; --t) {
        const double on = (t >= 1) ? 1.0 : 0.0;     // C[0] == 0
        double Vb0 = v00*dt3 + v01*dt2 + v02*dt;
        double Vb1 = v01*dt3 + v11*dt2 + v12*dt;
        double Vb2 = v02*dt3 + v12*dt2 + v22*dt;
        double Quu = on*0.1 + dt3*Vb0 + dt2*Vb1 + dt*Vb2;
        double Qxu0 = Vb0;
        double Qxu1 = dt*Vb0 + Vb1;
        double Qxu2 = dt2*Vb0 + dt*Vb1 + Vb2;
        double M01 = dt*v00 + v01;
        double M02 = dt2*v00 + dt*v01 + v02;
        double M11 = dt*v01 + v11;
        double M12 = dt2*v01 + dt*v11 + v12;
        double M22 = dt2*v02 + dt*v12 + v22;
        double Q00 = on*cxp + v00;
        double Q11 = on*cxv + dt*M01 + M11;
        double Q12 = dt*M02 + M12;
        double Q22 = on*1.0 + dt2*M02 + dt*M12 + M22;
        double m = -1.0 / Quu;
        T.qx0[t] = (float)Qxu0; T.qx1[t] = (float)Qxu1; T.qx2[t] = (float)Qxu2;
        T.dm[t]  = (float)(dt * m);
        T.k0[t]  = (float)(Qxu0*m); T.k1[t] = (float)(Qxu1*m); T.k2[t] = (float)(Qxu2*m);
        v00 = Q00 + m*Qxu0*Qxu0;               // Vn = Qxx + m*Qxu*Qxu^T
        v01 = M01 + m*Qxu0*Qxu1;               // (Qux + Quu*K == 0)
        v02 = M02 + m*Qxu0*Qxu2;
        v11 = Q11 + m*Qxu1*Qxu1;
        v12 = Q12 + m*Qxu1*Qxu2;
        v22 = Q22 + m*Qxu2*Qxu2;
    }
    return T;
}

// Register-resident recursion. `row` = &sm[bb*RS + axis]; all offsets
// compile-time constants after unroll; kk[] indices constant -> VGPRs.
template <int TY>
__device__ __forceinline__ void do_axis(float* __restrict__ row,
                                        float p, float ve, float ac) {
    constexpr Tbl T = make_tbl(TY);
    constexpr float wp = TY ? 10.f : 1.f;
    float kk[80];

    // ---- backward: v-recursion in registers; tg reads are off-chain ----
    float v0 = 0.f, v1 = 0.f, v2 = 0.f;
#pragma unroll
    for (int t = 80; t >= 1; --t) {
        float tg = row[(t - 1) * 3];           // independent address, batchable
        float a1 = fmaf(0.1f, v0, v1);
        float a2 = fmaf(0.1f, a1, v2);
        float k  = T.dm[t] * a2;               // k_t = -(b^T v)/Quu
        v0 = fmaf(T.qx0[t], k, v0) - wp * tg;
        v1 = fmaf(T.qx1[t], k, a1);
        v2 = fmaf(T.qx2[t], k, a2);
        if (t <= 79) kk[t] = k;                // k_80 never used by forward
    }
    {   // t = 0: C==0
        float a1 = fmaf(0.1f, v0, v1);
        float a2 = fmaf(0.1f, a1, v2);
        kk[0] = T.dm[0] * a2;
    }

    // ---- forward rollout: pure-register; p_t lands in OUTPUT layout ----
#pragma unroll
    for (int t = 0; t < 80; ++t) {
        float u  = fmaf(T.k0[t], p, fmaf(T.k1[t], ve, fmaf(T.k2[t], ac, kk[t])));
        float pn = fmaf(0.001f, u, fmaf(0.01f, ac, fmaf(0.1f, ve, p)));
        float vn = fmaf(0.01f,  u, fmaf(0.1f,  ac, ve));
        ac = fmaf(0.1f, u, ac);
        p = pn; ve = vn;
        row[t * 3] = p;                        // slot t*3+axis == out[t][axis]
    }
}

// ---------------------------------------------------------------------------
// BPB = 16 batches/block, NTH = 96, grid = 512 -> 2 blocks/CU (LDS 15.6 KB).
// Recursion: wave0 lanes 0..31 = axes 0,1 (type 0, uniform); wave1 lanes
// 0..15 = yaw (type 1, uniform). Staging/writeback: all 96 threads, fully
// unrolled (10 float4 each) so all global loads issue before the first wait.
// LDS stride 244: recursion-phase banks = (bb*20 + 3s + axis)%32 -> 2-way
// (free); staging/writeback are float4 bursts.
// ---------------------------------------------------------------------------
#define BPB 16
#define RS  244
#define NTH 96

__global__ __launch_bounds__(NTH) void lqr_fused_kernel(
        const float* __restrict__ ego,   // (8192, 9)
        const float* __restrict__ ap,    // (8192, 6, 80, 3)
        float* __restrict__ out) {       // (8192, 80, 3)
    __shared__ float sm[BPB * RS];       // 15616 B
    const int tid = threadIdx.x;
    const int b0  = blockIdx.x * BPB;

    // ---- stage targets: 16 batches x 60 float4 = 960; 10 per thread ----
#pragma unroll
    for (int j = 0; j < 10; ++j) {
        const int i  = tid + NTH * j;
        const int bb = i / 60, c = i - bb * 60;
        *(float4*)&sm[bb * RS + 4 * c] =
            *(const float4*)(ap + (size_t)(b0 + bb) * 1440 + 1200 + 4 * c);
    }

    // ---- recursion role assignment (wave-uniform type) ----
    const int w    = tid >> 6;           // 0: axes 0,1 | 1: yaw
    const int lane = tid & 63;
    const bool act = (w == 0) ? (lane < 32) : (lane < 16);
    const int bb   = (w == 0) ? (lane & 15) : lane;
    const int axis = (w == 0) ? (lane >> 4) : 2;
    const int b    = b0 + bb;

    // ego loads issued pre-barrier, consumed only at forward start
    float xp = 0.f, xv = 0.f, xa = 0.f;
    if (act) {
        xp = ego[b * 9 + axis];
        xv = ego[b * 9 + 3 + axis];
        xa = ego[b * 9 + 6 + axis];
    }
    __syncthreads();

    if (w == 0) { if (act) do_axis<0>(sm + bb * RS + axis, xp, xv, xa); }
    else        { if (act) do_axis<1>(sm + bb * RS + axis, xp, xv, xa); }
    __syncthreads();

    // ---- writeback: contiguous copy (LDS already in out layout) ----
#pragma unroll
    for (int j = 0; j < 10; ++j) {
        const int i  = tid + NTH * j;
        const int bb2 = i / 60, c = i - bb2 * 60;
        *(float4*)(out + (size_t)(b0 + bb2) * 240 + 4 * c) =
            *(const float4*)&sm[bb2 * RS + 4 * c];
    }
}

extern "C" void kernel_launch(void* const* d_in, const int* in_sizes, int n_in,
                              void* d_out, int out_size, void* d_ws, size_t ws_size,
                              hipStream_t stream) {
    const float* ego = (const float*)d_in[0];   // (8192, 9)
    const float* ap  = (const float*)d_in[1];   // (8192, 6, 80, 3)
    float*       out = (float*)d_out;           // (8192, 80, 3)
    lqr_fused_kernel<<<8192 / BPB, NTH, 0, stream>>>(ego, ap, out);
}